// Round 1
// baseline (9296.750 us; speedup 1.0000x reference)
//
#include <hip/hip_runtime.h>

// Problem constants (fixed by reference)
#define TT 256
#define FF 128
#define HH 256
#define BB 256
#define BTc (BB * TT)                    // 65536
#define BTFc ((size_t)BB * TT * FF)      // 8388608 elements per output tensor

typedef __attribute__((ext_vector_type(8))) short short8;
typedef __attribute__((ext_vector_type(4))) short short4v;
typedef __attribute__((ext_vector_type(4))) float floatx4;

__device__ __forceinline__ floatx4 mfma16(short8 a, short8 b, floatx4 c) {
    return __builtin_amdgcn_mfma_f32_16x16x32_bf16(a, b, c, 0, 0, 0);
}

__device__ __forceinline__ float bf2f(short s) {
    return __uint_as_float(((unsigned)(unsigned short)s) << 16);
}
__device__ __forceinline__ short f2bf(float f) {  // RNE
    unsigned u = __float_as_uint(f);
    u += 0x7FFFu + ((u >> 16) & 1u);
    return (short)(u >> 16);
}
__device__ __forceinline__ short8 ld_cvt8(const float* __restrict__ p) {
    short8 r;
#pragma unroll
    for (int j = 0; j < 8; ++j) r[j] = f2bf(p[j]);
    return r;
}
__device__ __forceinline__ float sigf(float x) { return 1.f / (1.f + __expf(-x)); }
__device__ __forceinline__ float tanhf_(float x) { return 1.f - 2.f / (1.f + __expf(2.f * x)); }

// ---------------------------------------------------------------------------
// k_prep: cast phase-A weight matrices fp32 -> bf16 (flat copies)
// segments: lagW_f, lagW_b, rbW_f, rbW_b (32768 ea), betaW_f, betaW_b (98304 ea), testW (49152)
// ---------------------------------------------------------------------------
struct PrepArgs {
    const float *s0, *s1, *s2, *s3, *s4, *s5, *s6;
    short *d0, *d1, *d2, *d3, *d4, *d5, *d6;
};
__global__ __launch_bounds__(256) void k_prep(PrepArgs P) {
    int i = blockIdx.x * 256 + threadIdx.x;
    if (i < 32768) { P.d0[i] = f2bf(P.s0[i]); return; }  i -= 32768;
    if (i < 32768) { P.d1[i] = f2bf(P.s1[i]); return; }  i -= 32768;
    if (i < 32768) { P.d2[i] = f2bf(P.s2[i]); return; }  i -= 32768;
    if (i < 32768) { P.d3[i] = f2bf(P.s3[i]); return; }  i -= 32768;
    if (i < 98304) { P.d4[i] = f2bf(P.s4[i]); return; }  i -= 98304;
    if (i < 98304) { P.d5[i] = f2bf(P.s5[i]); return; }  i -= 98304;
    if (i < 49152) { P.d6[i] = f2bf(P.s6[i]); return; }
}

// ---------------------------------------------------------------------------
// k_rr_rb: fused  rr = exp(-relu(lt @ lagW^T + lagb))  [BT,256] (bf16 out)
//                 rb = rr @ rbW^T + rbb                [BT,128] (bf16 out)
// 128 rows per block, 256 threads (4 waves). rr tile kept in LDS for stage 2.
// ---------------------------------------------------------------------------
__global__ __launch_bounds__(256) void k_rr_rb(
    const float* __restrict__ lt, const short* __restrict__ lagW,
    const float* __restrict__ lagb, const short* __restrict__ rbW,
    const float* __restrict__ rbb, short* __restrict__ rr, short* __restrict__ rb) {
    __shared__ short rrS[128][264];
    const int tid = threadIdx.x, lane = tid & 63, w = tid >> 6;
    const int ln = lane & 15, q4 = lane >> 4;
    const size_t r0 = (size_t)blockIdx.x * 128;

    // stage 1: rr
#pragma unroll
    for (int mt = 0; mt < 2; ++mt) {
        const int rbase = w * 32 + mt * 16;
        floatx4 acc[16];
#pragma unroll
        for (int nt = 0; nt < 16; ++nt) { floatx4 z = {0.f, 0.f, 0.f, 0.f}; acc[nt] = z; }
#pragma unroll
        for (int kt = 0; kt < 4; ++kt) {
            short8 a = ld_cvt8(lt + (r0 + rbase + ln) * 128 + kt * 32 + q4 * 8);
#pragma unroll
            for (int nt = 0; nt < 16; ++nt) {
                short8 b = *(const short8*)(lagW + (nt * 16 + ln) * 128 + kt * 32 + q4 * 8);
                acc[nt] = mfma16(a, b, acc[nt]);
            }
        }
#pragma unroll
        for (int nt = 0; nt < 16; ++nt) {
            int n = nt * 16 + ln;
            float bias = lagb[n];
#pragma unroll
            for (int r = 0; r < 4; ++r) {
                int row = rbase + q4 * 4 + r;
                rrS[row][n] = f2bf(__expf(-fmaxf(acc[nt][r] + bias, 0.f)));
            }
        }
    }
    __syncthreads();
    // coalesced rr writeback
    for (int c = tid; c < 128 * 32; c += 256) {
        int row = c >> 5, c8 = (c & 31) * 8;
        *(short8*)(rr + (r0 + row) * 256 + c8) = *(const short8*)&rrS[row][c8];
    }
    // stage 2: rb
#pragma unroll
    for (int mt = 0; mt < 2; ++mt) {
        const int rbase = w * 32 + mt * 16;
        floatx4 acc[8];
#pragma unroll
        for (int nt = 0; nt < 8; ++nt) { floatx4 z = {0.f, 0.f, 0.f, 0.f}; acc[nt] = z; }
#pragma unroll
        for (int kt = 0; kt < 8; ++kt) {
            short8 a = *(const short8*)&rrS[rbase + ln][kt * 32 + q4 * 8];
#pragma unroll
            for (int nt = 0; nt < 8; ++nt) {
                short8 b = *(const short8*)(rbW + (nt * 16 + ln) * 256 + kt * 32 + q4 * 8);
                acc[nt] = mfma16(a, b, acc[nt]);
            }
        }
#pragma unroll
        for (int nt = 0; nt < 8; ++nt) {
            int n = nt * 16 + ln;
            float bias = rbb[n];
#pragma unroll
            for (int r = 0; r < 4; ++r) {
                int row = rbase + q4 * 4 + r;
                rb[(r0 + row) * 128 + n] = f2bf(acc[nt][r] + bias);
            }
        }
    }
}

// ---------------------------------------------------------------------------
// k_beta: fused  u = sigmoid(concat(m, rb) @ bW^T + bb)   [BT,384] (LDS)
//                beta = u @ tW^T + tb                     [BT,128] (bf16 out)
// ---------------------------------------------------------------------------
__global__ __launch_bounds__(256) void k_beta(
    const float* __restrict__ m, const short* __restrict__ rb,
    const short* __restrict__ bW, const float* __restrict__ bb,
    const short* __restrict__ tW, const float* __restrict__ tb,
    short* __restrict__ bout) {
    __shared__ short uS[128][392];
    const int tid = threadIdx.x, lane = tid & 63, w = tid >> 6;
    const int ln = lane & 15, q4 = lane >> 4;
    const size_t r0 = (size_t)blockIdx.x * 128;

#pragma unroll
    for (int mt = 0; mt < 2; ++mt) {
        const int rbase = w * 32 + mt * 16;
        floatx4 acc[24];
#pragma unroll
        for (int nt = 0; nt < 24; ++nt) { floatx4 z = {0.f, 0.f, 0.f, 0.f}; acc[nt] = z; }
#pragma unroll
        for (int kt = 0; kt < 8; ++kt) {
            short8 a;
            if (kt < 4) a = ld_cvt8(m + (r0 + rbase + ln) * 128 + kt * 32 + q4 * 8);
            else        a = *(const short8*)(rb + (r0 + rbase + ln) * 128 + (kt - 4) * 32 + q4 * 8);
#pragma unroll
            for (int nt = 0; nt < 24; ++nt) {
                short8 b = *(const short8*)(bW + (nt * 16 + ln) * 256 + kt * 32 + q4 * 8);
                acc[nt] = mfma16(a, b, acc[nt]);
            }
        }
#pragma unroll
        for (int nt = 0; nt < 24; ++nt) {
            int n = nt * 16 + ln;
            float bias = bb[n];
#pragma unroll
            for (int r = 0; r < 4; ++r) {
                int row = rbase + q4 * 4 + r;
                uS[row][n] = f2bf(sigf(acc[nt][r] + bias));
            }
        }
    }
    __syncthreads();
#pragma unroll
    for (int mt = 0; mt < 2; ++mt) {
        const int rbase = w * 32 + mt * 16;
        floatx4 acc[8];
#pragma unroll
        for (int nt = 0; nt < 8; ++nt) { floatx4 z = {0.f, 0.f, 0.f, 0.f}; acc[nt] = z; }
#pragma unroll
        for (int kt = 0; kt < 12; ++kt) {
            short8 a = *(const short8*)&uS[rbase + ln][kt * 32 + q4 * 8];
#pragma unroll
            for (int nt = 0; nt < 8; ++nt) {
                short8 b = *(const short8*)(tW + (nt * 16 + ln) * 384 + kt * 32 + q4 * 8);
                acc[nt] = mfma16(a, b, acc[nt]);
            }
        }
#pragma unroll
        for (int nt = 0; nt < 8; ++nt) {
            int n = nt * 16 + ln;
            float bias = tb[n];
#pragma unroll
            for (int r = 0; r < 4; ++r) {
                int row = rbase + q4 * 4 + r;
                bout[(r0 + row) * 128 + n] = f2bf(acc[nt][r] + bias);
            }
        }
    }
}

// ---------------------------------------------------------------------------
// k_scan: persistent recurrent scan. 32 blocks = 2 dirs x 16 batch-groups of 16.
// 1024 threads = 16 waves. Weights pinned in VGPRs; no inter-block sync.
// Wave w owns gate n-tiles {w, w+16, w+32, w+48} == i/f/g/o for hidden cols
// [16w,16w+16): LSTM pointwise fully in registers, c state in VGPRs.
// ---------------------------------------------------------------------------
struct ScanArgs {
    const float* x; const float* m;
    const short* rr0; const short* rr1;
    const short* beta0; const short* beta1;
    const float* Wih0; const float* Whh0; const float* bih0; const float* bhh0;
    const float* Wih1; const float* Whh1; const float* bih1; const float* bhh1;
    const float* linW0; const float* linb0; const float* linW1; const float* linb1;
    const float* zW0; const float* zb0; const float* zW1; const float* zb1;
    float* out;
};

__global__ __launch_bounds__(1024) void k_scan(ScanArgs A) {
    const int tid = threadIdx.x;
    const int lane = tid & 63;
    const int w = tid >> 6;       // 0..15
    const int ln = lane & 15;
    const int q4 = lane >> 4;     // 0..3
    const int dir = blockIdx.x >> 4;
    const int bg0 = (blockIdx.x & 15) * 16;

    const short* rr   = dir ? A.rr1   : A.rr0;
    const short* beta = dir ? A.beta1 : A.beta0;
    const float* Wih  = dir ? A.Wih1  : A.Wih0;
    const float* Whh  = dir ? A.Whh1  : A.Whh0;
    const float* bih  = dir ? A.bih1  : A.bih0;
    const float* bhh  = dir ? A.bhh1  : A.bhh0;
    const float* linW = dir ? A.linW1 : A.linW0;
    const float* linb = dir ? A.linb1 : A.linb0;
    const float* zW   = dir ? A.zW1   : A.zW0;
    const float* zb   = dir ? A.zb1   : A.zb0;

    __shared__ short hS[16][264];    // h (bf16), padded: 2-way bank aliasing only
    __shared__ short hrS[16][264];   // h * r(t) (bf16)
    __shared__ short msS[16][136];   // m(t) bf16 (A-frags for gate k=128..255)
    __shared__ short xcS[16][136];   // x_c bf16
    __shared__ short ccS[16][136];   // c_c bf16
    __shared__ float outS[16][132];  // out fp32
    __shared__ float zS[16][132];    // z fp32

    // ---- persistent weight fragments (loaded once, live in VGPRs) ----
    short8 WihF[4][8], WhhF[4][8], OF[8];
#pragma unroll
    for (int q = 0; q < 4; ++q) {
        int n = (w + 16 * q) * 16 + ln;
#pragma unroll
        for (int kt = 0; kt < 8; ++kt) {
            WihF[q][kt] = ld_cvt8(Wih + (size_t)n * 256 + kt * 32 + q4 * 8);
            WhhF[q][kt] = ld_cvt8(Whh + (size_t)n * 256 + kt * 32 + q4 * 8);
        }
    }
    if (w < 8) {  // lin_W fragments (out-GEMM), n-tile = w
        int n = w * 16 + ln;
#pragma unroll
        for (int kt = 0; kt < 8; ++kt)
            OF[kt] = ld_cvt8(linW + (size_t)n * 256 + kt * 32 + q4 * 8);
    } else {      // z_W fragments with off-diagonal mask, n-tile = w-8
        int n = (w - 8) * 16 + ln;
#pragma unroll
        for (int kt = 0; kt < 4; ++kt) {
            const float* p = zW + (size_t)n * 128 + kt * 32 + q4 * 8;
            short8 v;
#pragma unroll
            for (int j = 0; j < 8; ++j) {
                int k = kt * 32 + q4 * 8 + j;
                v[j] = (k == n) ? (short)0 : f2bf(p[j]);
            }
            OF[kt] = v;
        }
    }
    float gb[4];
#pragma unroll
    for (int q = 0; q < 4; ++q) {
        int n = (w + 16 * q) * 16 + ln;
        gb[q] = bih[n] + bhh[n];
    }
    const float lb = (w < 8) ? linb[w * 16 + ln] : zb[(w - 8) * 16 + ln];

    // zero init h, h*r (h0 = c0 = 0)
    for (int i = tid; i < 16 * 264; i += 1024) { hS[i / 264][i % 264] = 0; hrS[i / 264][i % 264] = 0; }
    floatx4 cfr = {0.f, 0.f, 0.f, 0.f};  // c state (C-layout frag, wave-private)

    // pre-stage m(t0) into msS
    const int tfirst = dir ? (TT - 1) : 0;
    size_t rowoff0 = ((size_t)(bg0 + w) * TT + tfirst) * FF;
    float2 m2 = *(const float2*)(A.m + rowoff0 + lane * 2);
    msS[w][lane * 2 + 0] = f2bf(m2.x);
    msS[w][lane * 2 + 1] = f2bf(m2.y);
    __syncthreads();

    for (int tt = 0; tt < TT; ++tt) {
        const int t = dir ? (TT - 1 - tt) : tt;
        const int tn = dir ? (t > 0 ? t - 1 : 0) : (t < TT - 1 ? t + 1 : TT - 1);
        const size_t rowoff  = ((size_t)(bg0 + w) * TT + t) * FF;
        const size_t rowoffn = ((size_t)(bg0 + w) * TT + tn) * FF;

        // ---- step-start prefetches (consumed much later; latency hidden) ----
        float2 x2 = *(const float2*)(A.x + rowoff + lane * 2);
        short bv0 = beta[rowoff + lane * 2];
        short bv1 = beta[rowoff + lane * 2 + 1];
        float2 m2n = *(const float2*)(A.m + rowoffn + lane * 2);
        short rrn4[4];  // rr(t_next) at (batch row q4*4+r, hidden col w*16+ln) for P7
#pragma unroll
        for (int r = 0; r < 4; ++r)
            rrn4[r] = rr[((size_t)(bg0 + q4 * 4 + r) * TT + tn) * HH + w * 16 + ln];

        // ---- P1: gates (Whh on h*r, Wih m-part) + out GEMM (waves 0-7) ----
        floatx4 g[4];
#pragma unroll
        for (int q = 0; q < 4; ++q) { floatx4 v = {gb[q], gb[q], gb[q], gb[q]}; g[q] = v; }
#pragma unroll
        for (int kt = 0; kt < 8; ++kt) {
            short8 hrf = *(const short8*)&hrS[ln][kt * 32 + q4 * 8];
#pragma unroll
            for (int q = 0; q < 4; ++q) g[q] = mfma16(hrf, WhhF[q][kt], g[q]);
        }
#pragma unroll
        for (int kt = 0; kt < 4; ++kt) {
            short8 mf = *(const short8*)&msS[ln][kt * 32 + q4 * 8];
#pragma unroll
            for (int q = 0; q < 4; ++q) g[q] = mfma16(mf, WihF[q][kt + 4], g[q]);
        }
        if (w < 8) {
            floatx4 ov = {lb, lb, lb, lb};
#pragma unroll
            for (int kt = 0; kt < 8; ++kt) {
                short8 hf = *(const short8*)&hS[ln][kt * 32 + q4 * 8];
                ov = mfma16(hf, OF[kt], ov);
            }
#pragma unroll
            for (int r = 0; r < 4; ++r) outS[q4 * 4 + r][w * 16 + ln] = ov[r];
        }
        __syncthreads();  // A: outS ready

        // ---- P3: x_c = m*x + (1-m)*out ----
        float o0 = outS[w][lane * 2 + 0];
        float o1 = outS[w][lane * 2 + 1];
        xcS[w][lane * 2 + 0] = f2bf(m2.x * x2.x + (1.f - m2.x) * o0);
        xcS[w][lane * 2 + 1] = f2bf(m2.y * x2.y + (1.f - m2.y) * o1);
        __syncthreads();  // B: xcS ready

        // ---- P4: z = x_c @ (zW*offdiag)^T + zb  (waves 8-15) ----
        if (w >= 8) {
            floatx4 zv = {lb, lb, lb, lb};
#pragma unroll
            for (int kt = 0; kt < 4; ++kt) {
                short8 xf = *(const short8*)&xcS[ln][kt * 32 + q4 * 8];
                zv = mfma16(xf, OF[kt], zv);
            }
#pragma unroll
            for (int r = 0; r < 4; ++r) zS[q4 * 4 + r][(w - 8) * 16 + ln] = zv[r];
        }
        __syncthreads();  // C: zS ready

        // ---- P5: c_val, c_c, store outputs ----
        float z0 = zS[w][lane * 2 + 0];
        float z1 = zS[w][lane * 2 + 1];
        float b0 = bf2f(bv0), b1 = bf2f(bv1);
        float cv0 = b0 * z0 + (1.f - b0) * o0;
        float cv1 = b1 * z1 + (1.f - b1) * o1;
        float cc0 = m2.x * x2.x + (1.f - m2.x) * cv0;
        float cc1 = m2.y * x2.y + (1.f - m2.y) * cv1;
        ccS[w][lane * 2 + 0] = f2bf(cc0);
        ccS[w][lane * 2 + 1] = f2bf(cc1);
        {
            size_t ob = (size_t)dir * 3 * BTFc + rowoff + lane * 2;
            float2 v;
            v.x = o0;  v.y = o1;  *(float2*)(A.out + ob) = v;
            v.x = z0;  v.y = z1;  *(float2*)(A.out + ob + BTFc) = v;
            v.x = cv0; v.y = cv1; *(float2*)(A.out + ob + 2 * BTFc) = v;
        }
        __syncthreads();  // D: ccS ready

        // ---- P6: gates c_c part ----
#pragma unroll
        for (int kt = 0; kt < 4; ++kt) {
            short8 cf = *(const short8*)&ccS[ln][kt * 32 + q4 * 8];
#pragma unroll
            for (int q = 0; q < 4; ++q) g[q] = mfma16(cf, WihF[q][kt], g[q]);
        }

        // ---- P7: LSTM pointwise in registers; stage h, h*r(t+1), m(t+1) ----
#pragma unroll
        for (int r = 0; r < 4; ++r) {
            float gi = g[0][r], gf = g[1][r], gg = g[2][r], go = g[3][r];
            float c2 = sigf(gf) * cfr[r] + sigf(gi) * tanhf_(gg);
            float h2 = sigf(go) * tanhf_(c2);
            cfr[r] = c2;
            hS[q4 * 4 + r][w * 16 + ln] = f2bf(h2);
            hrS[q4 * 4 + r][w * 16 + ln] = f2bf(h2 * bf2f(rrn4[r]));
        }
        msS[w][lane * 2 + 0] = f2bf(m2n.x);
        msS[w][lane * 2 + 1] = f2bf(m2n.y);
        m2 = m2n;
        __syncthreads();  // E: h/hr/ms ready for next step
    }
}

// ---------------------------------------------------------------------------
extern "C" void kernel_launch(void* const* d_in, const int* in_sizes, int n_in,
                              void* d_out, int out_size, void* d_ws, size_t ws_size,
                              hipStream_t stream) {
    (void)in_sizes; (void)n_in; (void)out_size; (void)ws_size;
    const float* x        = (const float*)d_in[0];
    const float* m        = (const float*)d_in[1];
    const float* lt       = (const float*)d_in[2];
    const float* fw_Wih   = (const float*)d_in[3];
    const float* fw_Whh   = (const float*)d_in[4];
    const float* fw_bih   = (const float*)d_in[5];
    const float* fw_bhh   = (const float*)d_in[6];
    const float* bw_Wih   = (const float*)d_in[7];
    const float* bw_Whh   = (const float*)d_in[8];
    const float* bw_bih   = (const float*)d_in[9];
    const float* bw_bhh   = (const float*)d_in[10];
    const float* fwlin_W  = (const float*)d_in[11];
    const float* fwlin_b  = (const float*)d_in[12];
    const float* bwlin_W  = (const float*)d_in[13];
    const float* bwlin_b  = (const float*)d_in[14];
    const float* fwz_W    = (const float*)d_in[15];
    const float* fwz_b    = (const float*)d_in[16];
    const float* bwz_W    = (const float*)d_in[17];
    const float* bwz_b    = (const float*)d_in[18];
    const float* fwbeta_W = (const float*)d_in[19];
    const float* fwbeta_b = (const float*)d_in[20];
    const float* bwbeta_W = (const float*)d_in[21];
    const float* bwbeta_b = (const float*)d_in[22];
    const float* lag_W    = (const float*)d_in[23];
    const float* lag_b    = (const float*)d_in[24];
    const float* lagb_W   = (const float*)d_in[25];
    const float* lagb_b   = (const float*)d_in[26];
    const float* rbeta_W  = (const float*)d_in[27];
    const float* rbeta_b  = (const float*)d_in[28];
    const float* rbetab_W = (const float*)d_in[29];
    const float* rbetab_b = (const float*)d_in[30];
    const float* test_W   = (const float*)d_in[31];
    const float* test_b   = (const float*)d_in[32];

    char* ws = (char*)d_ws;
    size_t o = 0;
    short* lagW0b  = (short*)(ws + o); o += 32768 * 2;
    short* lagW1b  = (short*)(ws + o); o += 32768 * 2;
    short* rbW0b   = (short*)(ws + o); o += 32768 * 2;
    short* rbW1b   = (short*)(ws + o); o += 32768 * 2;
    short* betaW0b = (short*)(ws + o); o += 98304 * 2;
    short* betaW1b = (short*)(ws + o); o += 98304 * 2;
    short* testWb  = (short*)(ws + o); o += 49152 * 2;
    o = (size_t)1 << 20;  // align big buffers at 1 MB
    short* rr0 = (short*)(ws + o); o += (size_t)BTc * 256 * 2;
    short* rr1 = (short*)(ws + o); o += (size_t)BTc * 256 * 2;
    short* rb0 = (short*)(ws + o); o += (size_t)BTc * 128 * 2;
    short* rb1 = (short*)(ws + o); o += (size_t)BTc * 128 * 2;
    short* bt0 = (short*)(ws + o); o += (size_t)BTc * 128 * 2;
    short* bt1 = (short*)(ws + o); o += (size_t)BTc * 128 * 2;

    PrepArgs pa;
    pa.s0 = lag_W;    pa.d0 = lagW0b;
    pa.s1 = lagb_W;   pa.d1 = lagW1b;
    pa.s2 = rbeta_W;  pa.d2 = rbW0b;
    pa.s3 = rbetab_W; pa.d3 = rbW1b;
    pa.s4 = fwbeta_W; pa.d4 = betaW0b;
    pa.s5 = bwbeta_W; pa.d5 = betaW1b;
    pa.s6 = test_W;   pa.d6 = testWb;
    k_prep<<<1472, 256, 0, stream>>>(pa);

    k_rr_rb<<<BTc / 128, 256, 0, stream>>>(lt, lagW0b, lag_b,  rbW0b, rbeta_b,  rr0, rb0);
    k_rr_rb<<<BTc / 128, 256, 0, stream>>>(lt, lagW1b, lagb_b, rbW1b, rbetab_b, rr1, rb1);
    k_beta <<<BTc / 128, 256, 0, stream>>>(m, rb0, betaW0b, fwbeta_b, testWb, test_b, bt0);
    k_beta <<<BTc / 128, 256, 0, stream>>>(m, rb1, betaW1b, bwbeta_b, testWb, test_b, bt1);

    ScanArgs sa;
    sa.x = x; sa.m = m;
    sa.rr0 = rr0; sa.rr1 = rr1; sa.beta0 = bt0; sa.beta1 = bt1;
    sa.Wih0 = fw_Wih; sa.Whh0 = fw_Whh; sa.bih0 = fw_bih; sa.bhh0 = fw_bhh;
    sa.Wih1 = bw_Wih; sa.Whh1 = bw_Whh; sa.bih1 = bw_bih; sa.bhh1 = bw_bhh;
    sa.linW0 = fwlin_W; sa.linb0 = fwlin_b; sa.linW1 = bwlin_W; sa.linb1 = bwlin_b;
    sa.zW0 = fwz_W; sa.zb0 = fwz_b; sa.zW1 = bwz_W; sa.zb1 = bwz_b;
    sa.out = (float*)d_out;
    k_scan<<<32, 1024, 0, stream>>>(sa);
}

// Round 2
// 6577.876 us; speedup vs baseline: 1.4133x; 1.4133x over previous
//
#include <hip/hip_runtime.h>
#include <stdint.h>

// Problem constants (fixed by reference)
#define TT 256
#define FF 128
#define HH 256
#define BB 256
#define BTc (BB * TT)                    // 65536
#define BTFc ((size_t)BB * TT * FF)      // 8388608 elements per output tensor

typedef __attribute__((ext_vector_type(8))) short short8;
typedef __attribute__((ext_vector_type(4))) float floatx4;
typedef __attribute__((ext_vector_type(4))) int intx4;

__device__ __forceinline__ floatx4 mfma16(short8 a, short8 b, floatx4 c) {
    return __builtin_amdgcn_mfma_f32_16x16x32_bf16(a, b, c, 0, 0, 0);
}
__device__ __forceinline__ intx4 mfmai8(long a, long b, intx4 c) {
    return __builtin_amdgcn_mfma_i32_16x16x32_i8(a, b, c, 0, 0, 0);
}

__device__ __forceinline__ float bf2f(short s) {
    return __uint_as_float(((unsigned)(unsigned short)s) << 16);
}
__device__ __forceinline__ short f2bf(float f) {  // RNE
    unsigned u = __float_as_uint(f);
    u += 0x7FFFu + ((u >> 16) & 1u);
    return (short)(u >> 16);
}
__device__ __forceinline__ short8 ld_cvt8(const float* __restrict__ p) {
    short8 r;
#pragma unroll
    for (int j = 0; j < 8; ++j) r[j] = f2bf(p[j]);
    return r;
}
__device__ __forceinline__ float sigf(float x) { return 1.f / (1.f + __expf(-x)); }
__device__ __forceinline__ float tanhf_(float x) { return 1.f - 2.f / (1.f + __expf(2.f * x)); }

// ---------------------------------------------------------------------------
// k_prep: cast phase-A weight matrices fp32 -> bf16 (flat copies)
// ---------------------------------------------------------------------------
struct PrepArgs {
    const float *s0, *s1, *s2, *s3, *s4, *s5, *s6;
    short *d0, *d1, *d2, *d3, *d4, *d5, *d6;
};
__global__ __launch_bounds__(256) void k_prep(PrepArgs P) {
    int i = blockIdx.x * 256 + threadIdx.x;
    if (i < 32768) { P.d0[i] = f2bf(P.s0[i]); return; }  i -= 32768;
    if (i < 32768) { P.d1[i] = f2bf(P.s1[i]); return; }  i -= 32768;
    if (i < 32768) { P.d2[i] = f2bf(P.s2[i]); return; }  i -= 32768;
    if (i < 32768) { P.d3[i] = f2bf(P.s3[i]); return; }  i -= 32768;
    if (i < 98304) { P.d4[i] = f2bf(P.s4[i]); return; }  i -= 98304;
    if (i < 98304) { P.d5[i] = f2bf(P.s5[i]); return; }  i -= 98304;
    if (i < 49152) { P.d6[i] = f2bf(P.s6[i]); return; }
}

// ---------------------------------------------------------------------------
// k_scales: per-row absmax for i8 quantization. One wave per row.
// rows: whh0(1024), whh1(1024), wihm0(1024), wihm1(1024), lin0(128), lin1(128)
// ---------------------------------------------------------------------------
struct ScaleDesc { const float* src; int stride; int coloff; int K; int nrows; int sbase; };
struct ScaleArgs { ScaleDesc d[6]; float* s; };
__global__ __launch_bounds__(256) void k_scales(ScaleArgs A) {
    int gw = (blockIdx.x * 256 + threadIdx.x) >> 6;
    int lane = threadIdx.x & 63;
#pragma unroll 1
    for (int i = 0; i < 6; ++i) {
        if (gw < A.d[i].nrows) {
            const float* p = A.d[i].src + (size_t)gw * A.d[i].stride + A.d[i].coloff;
            float amax = 0.f;
            for (int j = lane; j < A.d[i].K; j += 64) amax = fmaxf(amax, fabsf(p[j]));
#pragma unroll
            for (int off = 32; off; off >>= 1) amax = fmaxf(amax, __shfl_xor(amax, off, 64));
            if (lane == 0) A.s[A.d[i].sbase + gw] = fmaxf(amax, 1e-20f);
            return;
        }
        gw -= A.d[i].nrows;
    }
}

// ---------------------------------------------------------------------------
// k_packq: fp32 [N,K] row-major -> i8 frag-major (16x16x32 MFMA B-frags)
// frag(nt,kt): byte off ((nt*kts+kt)*64+lane)*8 ; elem col = coloff+kt*32+q4*8+j
// ---------------------------------------------------------------------------
struct PackQDesc { const float* src; char* dst; int stride; int coloff; int kts; int sbase; int groups; };
struct PackQArgs { PackQDesc d[6]; const float* s; };
__global__ __launch_bounds__(256) void k_packq(PackQArgs A) {
    int g = blockIdx.x * 256 + threadIdx.x;
#pragma unroll 1
    for (int i = 0; i < 6; ++i) {
        const PackQDesc& D = A.d[i];
        if (g < D.groups) {
            int frag = g >> 6, lane = g & 63;
            int nt = frag / D.kts, kt = frag - nt * D.kts;
            int ln = lane & 15, q4 = lane >> 4;
            int row = nt * 16 + ln;
            const float* p = D.src + (size_t)row * D.stride + D.coloff + kt * 32 + q4 * 8;
            float inv = 127.f / A.s[D.sbase + row];
            char* dp = D.dst + (size_t)g * 8;
#pragma unroll
            for (int j = 0; j < 8; ++j) {
                int q = __float2int_rn(p[j] * inv);
                q = q > 127 ? 127 : (q < -127 ? -127 : q);
                dp[j] = (char)q;
            }
            return;
        }
        g -= D.groups;
    }
}

// ---------------------------------------------------------------------------
// k_packb: fp32 [N,K] row-major -> bf16 frag-major (optionally zero diagonal)
// ---------------------------------------------------------------------------
struct PackBDesc { const float* src; short* dst; int stride; int coloff; int kts; int diag; int groups; };
struct PackBArgs { PackBDesc d[4]; };
__global__ __launch_bounds__(256) void k_packb(PackBArgs A) {
    int g = blockIdx.x * 256 + threadIdx.x;
#pragma unroll 1
    for (int i = 0; i < 4; ++i) {
        const PackBDesc& D = A.d[i];
        if (g < D.groups) {
            int frag = g >> 6, lane = g & 63;
            int nt = frag / D.kts, kt = frag - nt * D.kts;
            int ln = lane & 15, q4 = lane >> 4;
            int row = nt * 16 + ln;
            const float* p = D.src + (size_t)row * D.stride + D.coloff + kt * 32 + q4 * 8;
            short* dp = D.dst + (size_t)g * 8;
#pragma unroll
            for (int j = 0; j < 8; ++j) {
                int col = kt * 32 + q4 * 8 + j;
                float v = p[j];
                if (D.diag && col == row) v = 0.f;
                dp[j] = f2bf(v);
            }
            return;
        }
        g -= D.groups;
    }
}

// ---------------------------------------------------------------------------
// k_rr_rb: fused  rr = exp(-relu(lt @ lagW^T + lagb))  [BT,256] (bf16 out)
//                 rb = rr @ rbW^T + rbb                [BT,128] (bf16 out)
// ---------------------------------------------------------------------------
__global__ __launch_bounds__(256) void k_rr_rb(
    const float* __restrict__ lt, const short* __restrict__ lagW,
    const float* __restrict__ lagb, const short* __restrict__ rbW,
    const float* __restrict__ rbb, short* __restrict__ rr, short* __restrict__ rb) {
    __shared__ short rrS[128][264];
    const int tid = threadIdx.x, lane = tid & 63, w = tid >> 6;
    const int ln = lane & 15, q4 = lane >> 4;
    const size_t r0 = (size_t)blockIdx.x * 128;

#pragma unroll
    for (int mt = 0; mt < 2; ++mt) {
        const int rbase = w * 32 + mt * 16;
        floatx4 acc[16];
#pragma unroll
        for (int nt = 0; nt < 16; ++nt) { floatx4 z = {0.f, 0.f, 0.f, 0.f}; acc[nt] = z; }
#pragma unroll
        for (int kt = 0; kt < 4; ++kt) {
            short8 a = ld_cvt8(lt + (r0 + rbase + ln) * 128 + kt * 32 + q4 * 8);
#pragma unroll
            for (int nt = 0; nt < 16; ++nt) {
                short8 b = *(const short8*)(lagW + (nt * 16 + ln) * 128 + kt * 32 + q4 * 8);
                acc[nt] = mfma16(a, b, acc[nt]);
            }
        }
#pragma unroll
        for (int nt = 0; nt < 16; ++nt) {
            int n = nt * 16 + ln;
            float bias = lagb[n];
#pragma unroll
            for (int r = 0; r < 4; ++r) {
                int row = rbase + q4 * 4 + r;
                rrS[row][n] = f2bf(__expf(-fmaxf(acc[nt][r] + bias, 0.f)));
            }
        }
    }
    __syncthreads();
    for (int c = tid; c < 128 * 32; c += 256) {
        int row = c >> 5, c8 = (c & 31) * 8;
        *(short8*)(rr + (r0 + row) * 256 + c8) = *(const short8*)&rrS[row][c8];
    }
#pragma unroll
    for (int mt = 0; mt < 2; ++mt) {
        const int rbase = w * 32 + mt * 16;
        floatx4 acc[8];
#pragma unroll
        for (int nt = 0; nt < 8; ++nt) { floatx4 z = {0.f, 0.f, 0.f, 0.f}; acc[nt] = z; }
#pragma unroll
        for (int kt = 0; kt < 8; ++kt) {
            short8 a = *(const short8*)&rrS[rbase + ln][kt * 32 + q4 * 8];
#pragma unroll
            for (int nt = 0; nt < 8; ++nt) {
                short8 b = *(const short8*)(rbW + (nt * 16 + ln) * 256 + kt * 32 + q4 * 8);
                acc[nt] = mfma16(a, b, acc[nt]);
            }
        }
#pragma unroll
        for (int nt = 0; nt < 8; ++nt) {
            int n = nt * 16 + ln;
            float bias = rbb[n];
#pragma unroll
            for (int r = 0; r < 4; ++r) {
                int row = rbase + q4 * 4 + r;
                rb[(r0 + row) * 128 + n] = f2bf(acc[nt][r] + bias);
            }
        }
    }
}

// ---------------------------------------------------------------------------
// k_beta: fused  u = sigmoid(concat(m, rb) @ bW^T + bb)   [BT,384] (LDS)
//                beta = u @ tW^T + tb                     [BT,128] (bf16 out)
// ---------------------------------------------------------------------------
__global__ __launch_bounds__(256) void k_beta(
    const float* __restrict__ m, const short* __restrict__ rb,
    const short* __restrict__ bW, const float* __restrict__ bb,
    const short* __restrict__ tW, const float* __restrict__ tb,
    short* __restrict__ bout) {
    __shared__ short uS[128][392];
    const int tid = threadIdx.x, lane = tid & 63, w = tid >> 6;
    const int ln = lane & 15, q4 = lane >> 4;
    const size_t r0 = (size_t)blockIdx.x * 128;

#pragma unroll
    for (int mt = 0; mt < 2; ++mt) {
        const int rbase = w * 32 + mt * 16;
        floatx4 acc[24];
#pragma unroll
        for (int nt = 0; nt < 24; ++nt) { floatx4 z = {0.f, 0.f, 0.f, 0.f}; acc[nt] = z; }
#pragma unroll
        for (int kt = 0; kt < 8; ++kt) {
            short8 a;
            if (kt < 4) a = ld_cvt8(m + (r0 + rbase + ln) * 128 + kt * 32 + q4 * 8);
            else        a = *(const short8*)(rb + (r0 + rbase + ln) * 128 + (kt - 4) * 32 + q4 * 8);
#pragma unroll
            for (int nt = 0; nt < 24; ++nt) {
                short8 b = *(const short8*)(bW + (nt * 16 + ln) * 256 + kt * 32 + q4 * 8);
                acc[nt] = mfma16(a, b, acc[nt]);
            }
        }
#pragma unroll
        for (int nt = 0; nt < 24; ++nt) {
            int n = nt * 16 + ln;
            float bias = bb[n];
#pragma unroll
            for (int r = 0; r < 4; ++r) {
                int row = rbase + q4 * 4 + r;
                uS[row][n] = f2bf(sigf(acc[nt][r] + bias));
            }
        }
    }
    __syncthreads();
#pragma unroll
    for (int mt = 0; mt < 2; ++mt) {
        const int rbase = w * 32 + mt * 16;
        floatx4 acc[8];
#pragma unroll
        for (int nt = 0; nt < 8; ++nt) { floatx4 z = {0.f, 0.f, 0.f, 0.f}; acc[nt] = z; }
#pragma unroll
        for (int kt = 0; kt < 12; ++kt) {
            short8 a = *(const short8*)&uS[rbase + ln][kt * 32 + q4 * 8];
#pragma unroll
            for (int nt = 0; nt < 8; ++nt) {
                short8 b = *(const short8*)(tW + (nt * 16 + ln) * 384 + kt * 32 + q4 * 8);
                acc[nt] = mfma16(a, b, acc[nt]);
            }
        }
#pragma unroll
        for (int nt = 0; nt < 8; ++nt) {
            int n = nt * 16 + ln;
            float bias = tb[n];
#pragma unroll
            for (int r = 0; r < 4; ++r) {
                int row = rbase + q4 * 4 + r;
                bout[(r0 + row) * 128 + n] = f2bf(acc[nt][r] + bias);
            }
        }
    }
}

// ---------------------------------------------------------------------------
// k_scan: persistent recurrent scan. 32 blocks = 2 dirs x 16 batch-groups.
// 16 waves. Whh pinned as i8 frags (64 VGPR/wave, fits 128-cap); Wih m-part
// i8 streamed (m is exactly {0,1}); Wih c-part bf16 streamed; lin i8
// streamed; zW bf16 in LDS. All streams L2-resident.
// ---------------------------------------------------------------------------
struct ScanArgs {
    const float* x; const float* m;
    const short* rr0; const short* rr1;
    const short* beta0; const short* beta1;
    const char* whh0; const char* whh1;
    const char* wihm0; const char* wihm1;
    const char* lin0; const char* lin1;
    const short* wihc0; const short* wihc1;
    const short* zw0; const short* zw1;
    const float* s_all;
    const float* bih0; const float* bhh0; const float* bih1; const float* bhh1;
    const float* linb0; const float* linb1; const float* zb0; const float* zb1;
    float* out;
};

__global__ __launch_bounds__(1024, 4) void k_scan(ScanArgs A) {
    const int tid = threadIdx.x;
    const int lane = tid & 63;
    const int w = tid >> 6;       // 0..15
    const int ln = lane & 15;
    const int q4 = lane >> 4;     // 0..3
    const int dir = blockIdx.x >> 4;
    const int bg0 = (blockIdx.x & 15) * 16;

    const short* rr    = dir ? A.rr1   : A.rr0;
    const short* beta  = dir ? A.beta1 : A.beta0;
    const char*  whhQ  = dir ? A.whh1  : A.whh0;
    const char*  wihmQ = dir ? A.wihm1 : A.wihm0;
    const char*  linQ  = dir ? A.lin1  : A.lin0;
    const short* wihcB = dir ? A.wihc1 : A.wihc0;
    const short* zwB   = dir ? A.zw1   : A.zw0;
    const float* bih   = dir ? A.bih1  : A.bih0;
    const float* bhh   = dir ? A.bhh1  : A.bhh0;
    const float* linb  = dir ? A.linb1 : A.linb0;
    const float* zb    = dir ? A.zb1   : A.zb0;
    const int so_whh  = dir ? 1024 : 0;
    const int so_wihm = 2048 + (dir ? 1024 : 0);
    const int so_lin  = 4096 + (dir ? 128 : 0);

    __shared__ char  hS8[16][264];    // h  in i8 (x127), pad 8 -> 2-bank row skew
    __shared__ char  hrS8[16][264];   // h*r in i8 (x127)
    __shared__ char  msS8[16][136];   // m in i8 {0,1}
    __shared__ short xcS[16][136];    // x_c bf16
    __shared__ short ccS[16][136];    // c_c bf16
    __shared__ short outS[16][136];   // out bf16
    __shared__ short zS[16][136];     // z bf16
    __shared__ short zwS[16384];      // masked zW, bf16 frag-major (32 KB)

    // ---- pinned Whh i8 fragments: 4 gates x 8 kt x 2 VGPR = 64 VGPRs ----
    long WhhP[4][8];
#pragma unroll
    for (int q = 0; q < 4; ++q)
#pragma unroll
        for (int kt = 0; kt < 8; ++kt)
            WhhP[q][kt] = *(const long*)(whhQ + (((w + 16 * q) * 8 + kt) * 512 + lane * 8));

    float fhh[4], fm[4], gb[4];
#pragma unroll
    for (int q = 0; q < 4; ++q) {
        int n = (w + 16 * q) * 16 + ln;
        fhh[q] = A.s_all[so_whh + n] * (1.f / 16129.f);   // (s/127)*(1/127)
        fm[q]  = A.s_all[so_wihm + n] * (1.f / 127.f);    // m stored as {0,1}
        gb[q]  = bih[n] + bhh[n];
    }
    float flin = 0.f, lb;
    if (w < 8) { int n = w * 16 + ln; flin = A.s_all[so_lin + n] * (1.f / 16129.f); lb = linb[n]; }
    else       { lb = zb[(w - 8) * 16 + ln]; }

    for (int i = tid; i < 16384; i += 1024) zwS[i] = zwB[i];
    for (int i = tid; i < 16 * 264; i += 1024) { hS8[i / 264][i % 264] = 0; hrS8[i / 264][i % 264] = 0; }

    const int tfirst = dir ? (TT - 1) : 0;
    float2 m2 = *(const float2*)(A.m + ((size_t)(bg0 + w) * TT + tfirst) * FF + lane * 2);
    msS8[w][lane * 2 + 0] = (char)(m2.x != 0.f);
    msS8[w][lane * 2 + 1] = (char)(m2.y != 0.f);
    floatx4 cfr = {0.f, 0.f, 0.f, 0.f};
    __syncthreads();

    for (int tt = 0; tt < TT; ++tt) {
        const int t = dir ? (TT - 1 - tt) : tt;
        const int tn = dir ? (t > 0 ? t - 1 : 0) : (t < TT - 1 ? t + 1 : t);
        const size_t rowoff  = ((size_t)(bg0 + w) * TT + t) * FF;
        const size_t rowoffn = ((size_t)(bg0 + w) * TT + tn) * FF;

        // ---- P0: prefetches (consumed much later; HBM latency hidden) ----
        float2 x2  = *(const float2*)(A.x + rowoff + lane * 2);
        float2 m2n = *(const float2*)(A.m + rowoffn + lane * 2);
        int bvi = *(const int*)(beta + rowoff + lane * 2);
        short rrn4[4];
#pragma unroll
        for (int r = 0; r < 4; ++r)
            rrn4[r] = rr[((size_t)(bg0 + q4 * 4 + r) * TT + tn) * HH + w * 16 + ln];

        // ---- P1: gates = Whh*(h*r) [i8 pinned] + WihM*m [i8 streamed] ----
        floatx4 g[4];
#pragma unroll
        for (int pass = 0; pass < 2; ++pass) {
            const int q0 = pass * 2, q1 = pass * 2 + 1;
            intx4 gi0 = {0, 0, 0, 0}, gi1 = {0, 0, 0, 0};
#pragma unroll
            for (int kt = 0; kt < 8; ++kt) {
                long hrf = *(const long*)&hrS8[ln][kt * 32 + q4 * 8];
                gi0 = mfmai8(hrf, WhhP[q0][kt], gi0);
                gi1 = mfmai8(hrf, WhhP[q1][kt], gi1);
            }
            intx4 mi0 = {0, 0, 0, 0}, mi1 = {0, 0, 0, 0};
#pragma unroll
            for (int kt = 0; kt < 4; ++kt) {
                long wm0 = *(const long*)(wihmQ + (((w + 16 * q0) * 4 + kt) * 512 + lane * 8));
                long wm1 = *(const long*)(wihmQ + (((w + 16 * q1) * 4 + kt) * 512 + lane * 8));
                long mf = *(const long*)&msS8[ln][kt * 32 + q4 * 8];
                mi0 = mfmai8(mf, wm0, mi0);
                mi1 = mfmai8(mf, wm1, mi1);
            }
#pragma unroll
            for (int r = 0; r < 4; ++r) {
                g[q0][r] = (float)gi0[r] * fhh[q0] + (float)mi0[r] * fm[q0] + gb[q0];
                g[q1][r] = (float)gi1[r] * fhh[q1] + (float)mi1[r] * fm[q1] + gb[q1];
            }
        }
        if (w < 8) {  // out = h @ linW^T + b   [i8 streamed]
            intx4 oi = {0, 0, 0, 0};
#pragma unroll
            for (int kt = 0; kt < 8; ++kt) {
                long lf = *(const long*)(linQ + ((w * 8 + kt) * 512 + lane * 8));
                long hf = *(const long*)&hS8[ln][kt * 32 + q4 * 8];
                oi = mfmai8(hf, lf, oi);
            }
#pragma unroll
            for (int r = 0; r < 4; ++r)
                outS[q4 * 4 + r][w * 16 + ln] = f2bf((float)oi[r] * flin + lb);
        }
        __syncthreads();  // A: outS ready

        // ---- P3: x_c ----
        float o0 = bf2f(outS[w][lane * 2 + 0]);
        float o1 = bf2f(outS[w][lane * 2 + 1]);
        float xc0 = m2.x * x2.x + (1.f - m2.x) * o0;
        float xc1 = m2.y * x2.y + (1.f - m2.y) * o1;
        xcS[w][lane * 2 + 0] = f2bf(xc0);
        xcS[w][lane * 2 + 1] = f2bf(xc1);
        __syncthreads();  // B: xcS ready

        // ---- P4: z = x_c @ (zW*offdiag)^T + zb  (waves 8-15, zW in LDS) ----
        if (w >= 8) {
            floatx4 zv = {lb, lb, lb, lb};
#pragma unroll
            for (int kt = 0; kt < 4; ++kt) {
                short8 xf = *(const short8*)&xcS[ln][kt * 32 + q4 * 8];
                short8 zf = *(const short8*)&zwS[((w - 8) * 4 + kt) * 512 + lane * 8];
                zv = mfma16(xf, zf, zv);
            }
#pragma unroll
            for (int r = 0; r < 4; ++r) zS[q4 * 4 + r][(w - 8) * 16 + ln] = f2bf(zv[r]);
        }
        __syncthreads();  // C: zS ready

        // ---- P5: c_val, c_c, store outputs ----
        float z0 = bf2f(zS[w][lane * 2 + 0]);
        float z1 = bf2f(zS[w][lane * 2 + 1]);
        float b0 = bf2f((short)(bvi & 0xffff));
        float b1 = bf2f((short)(((unsigned)bvi) >> 16));
        float cv0 = b0 * z0 + (1.f - b0) * o0;
        float cv1 = b1 * z1 + (1.f - b1) * o1;
        float cc0 = m2.x * x2.x + (1.f - m2.x) * cv0;
        float cc1 = m2.y * x2.y + (1.f - m2.y) * cv1;
        ccS[w][lane * 2 + 0] = f2bf(cc0);
        ccS[w][lane * 2 + 1] = f2bf(cc1);
        {
            size_t ob = (size_t)dir * 3 * BTFc + rowoff + lane * 2;
            float2 v;
            v.x = o0;  v.y = o1;  *(float2*)(A.out + ob) = v;
            v.x = z0;  v.y = z1;  *(float2*)(A.out + ob + BTFc) = v;
            v.x = cv0; v.y = cv1; *(float2*)(A.out + ob + 2 * BTFc) = v;
        }
        __syncthreads();  // D: ccS ready

        // ---- P6: gates += WihC * c_c  [bf16 streamed] ----
#pragma unroll
        for (int kt = 0; kt < 4; ++kt) {
            short8 ccf = *(const short8*)&ccS[ln][kt * 32 + q4 * 8];
#pragma unroll
            for (int q = 0; q < 4; ++q) {
                short8 wc = *(const short8*)(wihcB + ((w + 16 * q) * 4 + kt) * 512 + lane * 8);
                g[q] = mfma16(ccf, wc, g[q]);
            }
        }

        // ---- P7: LSTM pointwise; stage h, h*r(t+1), m(t+1) as i8 ----
#pragma unroll
        for (int r = 0; r < 4; ++r) {
            float gi_ = g[0][r], gf_ = g[1][r], gg_ = g[2][r], go_ = g[3][r];
            float c2 = sigf(gf_) * cfr[r] + sigf(gi_) * tanhf_(gg_);
            float h2 = sigf(go_) * tanhf_(c2);
            cfr[r] = c2;
            float rv = bf2f(rrn4[r]);
            hS8[q4 * 4 + r][w * 16 + ln]  = (char)__float2int_rn(h2 * 127.f);
            hrS8[q4 * 4 + r][w * 16 + ln] = (char)__float2int_rn(h2 * rv * 127.f);
        }
        msS8[w][lane * 2 + 0] = (char)(m2n.x != 0.f);
        msS8[w][lane * 2 + 1] = (char)(m2n.y != 0.f);
        m2 = m2n;
        __syncthreads();  // E
    }
}

// ---------------------------------------------------------------------------
extern "C" void kernel_launch(void* const* d_in, const int* in_sizes, int n_in,
                              void* d_out, int out_size, void* d_ws, size_t ws_size,
                              hipStream_t stream) {
    (void)in_sizes; (void)n_in; (void)out_size; (void)ws_size;
    const float* x        = (const float*)d_in[0];
    const float* m        = (const float*)d_in[1];
    const float* lt       = (const float*)d_in[2];
    const float* fw_Wih   = (const float*)d_in[3];
    const float* fw_Whh   = (const float*)d_in[4];
    const float* fw_bih   = (const float*)d_in[5];
    const float* fw_bhh   = (const float*)d_in[6];
    const float* bw_Wih   = (const float*)d_in[7];
    const float* bw_Whh   = (const float*)d_in[8];
    const float* bw_bih   = (const float*)d_in[9];
    const float* bw_bhh   = (const float*)d_in[10];
    const float* fwlin_W  = (const float*)d_in[11];
    const float* fwlin_b  = (const float*)d_in[12];
    const float* bwlin_W  = (const float*)d_in[13];
    const float* bwlin_b  = (const float*)d_in[14];
    const float* fwz_W    = (const float*)d_in[15];
    const float* fwz_b    = (const float*)d_in[16];
    const float* bwz_W    = (const float*)d_in[17];
    const float* bwz_b    = (const float*)d_in[18];
    const float* fwbeta_W = (const float*)d_in[19];
    const float* fwbeta_b = (const float*)d_in[20];
    const float* bwbeta_W = (const float*)d_in[21];
    const float* bwbeta_b = (const float*)d_in[22];
    const float* lag_W    = (const float*)d_in[23];
    const float* lag_b    = (const float*)d_in[24];
    const float* lagb_W   = (const float*)d_in[25];
    const float* lagb_b   = (const float*)d_in[26];
    const float* rbeta_W  = (const float*)d_in[27];
    const float* rbeta_b  = (const float*)d_in[28];
    const float* rbetab_W = (const float*)d_in[29];
    const float* rbetab_b = (const float*)d_in[30];
    const float* test_W   = (const float*)d_in[31];
    const float* test_b   = (const float*)d_in[32];

    char* ws = (char*)d_ws;
    size_t o = 0;
    auto alloc = [&](size_t bytes) { char* p = ws + o; o += (bytes + 255) & ~(size_t)255; return p; };
    short* lagW0b  = (short*)alloc(65536);
    short* lagW1b  = (short*)alloc(65536);
    short* rbW0b   = (short*)alloc(65536);
    short* rbW1b   = (short*)alloc(65536);
    short* betaW0b = (short*)alloc(196608);
    short* betaW1b = (short*)alloc(196608);
    short* testWb  = (short*)alloc(98304);
    float* s_all   = (float*)alloc(4352 * 4);
    char*  whhQ0   = (char*)alloc(262144);
    char*  whhQ1   = (char*)alloc(262144);
    char*  wihmQ0  = (char*)alloc(131072);
    char*  wihmQ1  = (char*)alloc(131072);
    char*  linQ0   = (char*)alloc(32768);
    char*  linQ1   = (char*)alloc(32768);
    short* wihcB0  = (short*)alloc(262144);
    short* wihcB1  = (short*)alloc(262144);
    short* zwB0    = (short*)alloc(32768);
    short* zwB1    = (short*)alloc(32768);
    o = (o + ((size_t)1 << 20) - 1) & ~(((size_t)1 << 20) - 1);
    short* rr0 = (short*)(ws + o); o += (size_t)BTc * 256 * 2;
    short* rr1 = (short*)(ws + o); o += (size_t)BTc * 256 * 2;
    short* rb0 = (short*)(ws + o); o += (size_t)BTc * 128 * 2;
    short* rb1 = (short*)(ws + o); o += (size_t)BTc * 128 * 2;
    short* bt0 = (short*)(ws + o); o += (size_t)BTc * 128 * 2;
    short* bt1 = (short*)(ws + o); o += (size_t)BTc * 128 * 2;

    PrepArgs pa;
    pa.s0 = lag_W;    pa.d0 = lagW0b;
    pa.s1 = lagb_W;   pa.d1 = lagW1b;
    pa.s2 = rbeta_W;  pa.d2 = rbW0b;
    pa.s3 = rbetab_W; pa.d3 = rbW1b;
    pa.s4 = fwbeta_W; pa.d4 = betaW0b;
    pa.s5 = bwbeta_W; pa.d5 = betaW1b;
    pa.s6 = test_W;   pa.d6 = testWb;
    k_prep<<<1472, 256, 0, stream>>>(pa);

    ScaleArgs sca;
    sca.d[0] = { fw_Whh,  256, 0,   256, 1024, 0 };
    sca.d[1] = { bw_Whh,  256, 0,   256, 1024, 1024 };
    sca.d[2] = { fw_Wih,  256, 128, 128, 1024, 2048 };
    sca.d[3] = { bw_Wih,  256, 128, 128, 1024, 3072 };
    sca.d[4] = { fwlin_W, 256, 0,   256, 128,  4096 };
    sca.d[5] = { bwlin_W, 256, 0,   256, 128,  4224 };
    sca.s = s_all;
    k_scales<<<1088, 256, 0, stream>>>(sca);

    PackQArgs pq;
    pq.d[0] = { fw_Whh,  whhQ0,  256, 0,   8, 0,    32768 };
    pq.d[1] = { bw_Whh,  whhQ1,  256, 0,   8, 1024, 32768 };
    pq.d[2] = { fw_Wih,  wihmQ0, 256, 128, 4, 2048, 16384 };
    pq.d[3] = { bw_Wih,  wihmQ1, 256, 128, 4, 3072, 16384 };
    pq.d[4] = { fwlin_W, linQ0,  256, 0,   8, 4096, 4096 };
    pq.d[5] = { bwlin_W, linQ1,  256, 0,   8, 4224, 4096 };
    pq.s = s_all;
    k_packq<<<416, 256, 0, stream>>>(pq);

    PackBArgs pb;
    pb.d[0] = { fw_Wih, wihcB0, 256, 0, 4, 0, 16384 };
    pb.d[1] = { bw_Wih, wihcB1, 256, 0, 4, 0, 16384 };
    pb.d[2] = { fwz_W,  zwB0,   128, 0, 4, 1, 2048 };
    pb.d[3] = { bwz_W,  zwB1,   128, 0, 4, 1, 2048 };
    k_packb<<<144, 256, 0, stream>>>(pb);

    k_rr_rb<<<BTc / 128, 256, 0, stream>>>(lt, lagW0b, lag_b,  rbW0b, rbeta_b,  rr0, rb0);
    k_rr_rb<<<BTc / 128, 256, 0, stream>>>(lt, lagW1b, lagb_b, rbW1b, rbetab_b, rr1, rb1);
    k_beta <<<BTc / 128, 256, 0, stream>>>(m, rb0, betaW0b, fwbeta_b, testWb, test_b, bt0);
    k_beta <<<BTc / 128, 256, 0, stream>>>(m, rb1, betaW1b, bwbeta_b, testWb, test_b, bt1);

    ScanArgs sa;
    sa.x = x; sa.m = m;
    sa.rr0 = rr0; sa.rr1 = rr1; sa.beta0 = bt0; sa.beta1 = bt1;
    sa.whh0 = whhQ0; sa.whh1 = whhQ1;
    sa.wihm0 = wihmQ0; sa.wihm1 = wihmQ1;
    sa.lin0 = linQ0; sa.lin1 = linQ1;
    sa.wihc0 = wihcB0; sa.wihc1 = wihcB1;
    sa.zw0 = zwB0; sa.zw1 = zwB1;
    sa.s_all = s_all;
    sa.bih0 = fw_bih; sa.bhh0 = fw_bhh; sa.bih1 = bw_bih; sa.bhh1 = bw_bhh;
    sa.linb0 = fwlin_b; sa.linb1 = bwlin_b; sa.zb0 = fwz_b; sa.zb1 = bwz_b;
    sa.out = (float*)d_out;
    k_scan<<<32, 1024, 0, stream>>>(sa);
}